// Round 1
// baseline (985.615 us; speedup 1.0000x reference)
//
#include <hip/hip_runtime.h>

#define NN 100000
#define NE 1600000

// ---------------- graph setup ----------------

__global__ __launch_bounds__(256) void k_init(float* deg, int* cnt, int* fill, int n) {
    int i = blockIdx.x * 256 + threadIdx.x;
    if (i < n) { deg[i] = 1.0f; cnt[i] = 0; fill[i] = 0; }   // 1.0 = self-loop weight
}

__global__ __launch_bounds__(256) void k_deg_cnt(const int* __restrict__ row,
                                                 const int* __restrict__ col,
                                                 const float* __restrict__ ew,
                                                 float* deg, int* cnt, int e) {
    int i = blockIdx.x * 256 + threadIdx.x;
    if (i < e) {
        int c = col[i];
        atomicAdd(&deg[c], ew[i]);
        atomicAdd(&cnt[c], 1);
    }
}

__global__ __launch_bounds__(256) void k_dinv(const float* __restrict__ deg, float* dinv, int n) {
    int i = blockIdx.x * 256 + threadIdx.x;
    if (i < n) { float d = deg[i]; dinv[i] = (d > 0.0f) ? rsqrtf(d) : 0.0f; }
}

// exclusive scan of cnt -> rowptr (3-phase: block scan, scan partials, add offsets)
__global__ __launch_bounds__(256) void k_scan1(const int* __restrict__ cnt,
                                               int* __restrict__ rowptr,
                                               int* __restrict__ part, int n) {
    __shared__ int s[256];
    int t = threadIdx.x;
    int i = blockIdx.x * 256 + t;
    int v = (i < n) ? cnt[i] : 0;
    s[t] = v;
    __syncthreads();
    for (int d = 1; d < 256; d <<= 1) {
        int y = (t >= d) ? s[t - d] : 0;
        __syncthreads();
        s[t] += y;
        __syncthreads();
    }
    if (i < n) rowptr[i] = s[t] - v;          // exclusive within block
    if (t == 255) part[blockIdx.x] = s[255];  // block total
}

__global__ __launch_bounds__(512) void k_scan2(int* part, int m) {
    __shared__ int s[512];
    int t = threadIdx.x;
    int v = (t < m) ? part[t] : 0;
    s[t] = v;
    __syncthreads();
    for (int d = 1; d < 512; d <<= 1) {
        int y = (t >= d) ? s[t - d] : 0;
        __syncthreads();
        s[t] += y;
        __syncthreads();
    }
    if (t < m) part[t] = s[t] - v;            // exclusive block offsets
}

__global__ __launch_bounds__(256) void k_scan3(int* rowptr, const int* __restrict__ part, int n, int e) {
    int i = blockIdx.x * 256 + threadIdx.x;
    if (i < n) rowptr[i] += part[blockIdx.x];
    if (i == 0) rowptr[n] = e;
}

// bucket-fill CSR: srcs[p] = source node, wn[p] = dinv[src]*ew*dinv[dst]
__global__ __launch_bounds__(256) void k_fill(const int* __restrict__ row,
                                              const int* __restrict__ col,
                                              const float* __restrict__ ew,
                                              const int* __restrict__ rowptr,
                                              int* fill, const float* __restrict__ dinv,
                                              int* __restrict__ srcs, float* __restrict__ wn, int e) {
    int i = blockIdx.x * 256 + threadIdx.x;
    if (i < e) {
        int c = col[i];
        int r = row[i];
        int p = rowptr[c] + atomicAdd(&fill[c], 1);
        srcs[p] = r;
        wn[p] = dinv[r] * ew[i] * dinv[c];
    }
}

// ---------------- fp32 GEMM: C[nx128] = A[nx128] @ W[128x128] ----------------
// 32 rows per block, all 128 cols. A tile + whole W staged in LDS (80 KB -> 2 blk/CU).
// Loads complete before any store (barrier), so C==A (in-place) is safe.
__global__ __launch_bounds__(256) void k_gemm(const float* __restrict__ A,
                                              const float* __restrict__ W,
                                              float* __restrict__ C) {
    __shared__ float sW[128 * 128];
    __shared__ float sA[32 * 128];
    int t = threadIdx.x;
    size_t r0 = (size_t)blockIdx.x * 32;

    const float4* W4 = (const float4*)W;
    float4* sW4 = (float4*)sW;
#pragma unroll
    for (int i = 0; i < 16; ++i) sW4[t + 256 * i] = W4[t + 256 * i];

    const float4* A4 = (const float4*)(A + r0 * 128);
    float4* sA4 = (float4*)sA;
#pragma unroll
    for (int i = 0; i < 4; ++i) sA4[t + 256 * i] = A4[t + 256 * i];
    __syncthreads();

    int rr = (t >> 5) << 2;   // 0,4,...,28
    int cc = (t & 31) << 2;   // 0,4,...,124
    float acc[4][4] = {{0.0f}};

#pragma unroll 2
    for (int k = 0; k < 128; k += 4) {
        float4 w0 = *(const float4*)&sW[(k + 0) * 128 + cc];
        float4 w1 = *(const float4*)&sW[(k + 1) * 128 + cc];
        float4 w2 = *(const float4*)&sW[(k + 2) * 128 + cc];
        float4 w3 = *(const float4*)&sW[(k + 3) * 128 + cc];
#pragma unroll
        for (int i = 0; i < 4; ++i) {
            float4 a = *(const float4*)&sA[(rr + i) * 128 + k];
            acc[i][0] = fmaf(a.x, w0.x, acc[i][0]);
            acc[i][1] = fmaf(a.x, w0.y, acc[i][1]);
            acc[i][2] = fmaf(a.x, w0.z, acc[i][2]);
            acc[i][3] = fmaf(a.x, w0.w, acc[i][3]);
            acc[i][0] = fmaf(a.y, w1.x, acc[i][0]);
            acc[i][1] = fmaf(a.y, w1.y, acc[i][1]);
            acc[i][2] = fmaf(a.y, w1.z, acc[i][2]);
            acc[i][3] = fmaf(a.y, w1.w, acc[i][3]);
            acc[i][0] = fmaf(a.z, w2.x, acc[i][0]);
            acc[i][1] = fmaf(a.z, w2.y, acc[i][1]);
            acc[i][2] = fmaf(a.z, w2.z, acc[i][2]);
            acc[i][3] = fmaf(a.z, w2.w, acc[i][3]);
            acc[i][0] = fmaf(a.w, w3.x, acc[i][0]);
            acc[i][1] = fmaf(a.w, w3.y, acc[i][1]);
            acc[i][2] = fmaf(a.w, w3.z, acc[i][2]);
            acc[i][3] = fmaf(a.w, w3.w, acc[i][3]);
        }
    }

#pragma unroll
    for (int i = 0; i < 4; ++i) {
        float4 o = make_float4(acc[i][0], acc[i][1], acc[i][2], acc[i][3]);
        *(float4*)&C[(r0 + rr + i) * 128 + cc] = o;
    }
}

// ---------------- pull-aggregation: one wave per node, 2 ch/lane ----------------
__global__ __launch_bounds__(256) void k_agg(const float* __restrict__ XW,
                                             const int* __restrict__ rowptr,
                                             const int* __restrict__ srcs,
                                             const float* __restrict__ wn,
                                             const float* __restrict__ dinv,
                                             const float* __restrict__ bias,
                                             float* __restrict__ out, int relu, int n) {
    int lane = threadIdx.x & 63;
    int node = blockIdx.x * 4 + (threadIdx.x >> 6);
    if (node >= n) return;
    int ch = lane * 2;

    float di = dinv[node];
    float selfw = di * di;   // self-loop norm: dinv*1*dinv
    float2 v = *(const float2*)(XW + (size_t)node * 128 + ch);
    float2 bv = *(const float2*)(bias + ch);
    float ax = fmaf(selfw, v.x, bv.x);
    float ay = fmaf(selfw, v.y, bv.y);

    int p0 = rowptr[node], p1 = rowptr[node + 1];
    for (int p = p0; p < p1; ++p) {
        int s = srcs[p];
        float w = wn[p];
        float2 u = *(const float2*)(XW + (size_t)s * 128 + ch);
        ax = fmaf(w, u.x, ax);
        ay = fmaf(w, u.y, ay);
    }
    if (relu) { ax = fmaxf(ax, 0.0f); ay = fmaxf(ay, 0.0f); }
    *(float2*)(out + (size_t)node * 128 + ch) = make_float2(ax, ay);
}

// ---------------- launcher ----------------
extern "C" void kernel_launch(void* const* d_in, const int* in_sizes, int n_in,
                              void* d_out, int out_size, void* d_ws, size_t ws_size,
                              hipStream_t stream) {
    const float* x  = (const float*)d_in[0];
    const int*   ei = (const int*)d_in[1];
    const float* ew = (const float*)d_in[2];
    const float* W1 = (const float*)d_in[3];
    const float* b1 = (const float*)d_in[4];
    const float* W2 = (const float*)d_in[5];
    const float* b2 = (const float*)d_in[6];
    const float* W3 = (const float*)d_in[7];
    const float* b3 = (const float*)d_in[8];
    float* out = (float*)d_out;

    const int n = NN, e = NE;
    const int* row = ei;        // edge_index[0]
    const int* col = ei + e;    // edge_index[1]

    char* ws = (char*)d_ws;
    size_t off = 0;
    auto alloc = [&](size_t bytes) -> void* {
        void* p = ws + off;
        off = (off + bytes + 255) & ~(size_t)255;
        return p;
    };
    float* h      = (float*)alloc((size_t)n * 128 * 4);  // 51.2 MB intermediate
    float* deg    = (float*)alloc((size_t)n * 4);
    float* dinv   = (float*)alloc((size_t)n * 4);
    int*   cnt    = (int*)  alloc((size_t)n * 4);
    int*   rowptr = (int*)  alloc((size_t)(n + 1) * 4);
    int*   fill   = (int*)  alloc((size_t)n * 4);
    int*   srcs   = (int*)  alloc((size_t)e * 4);
    float* wn     = (float*)alloc((size_t)e * 4);
    int*   part   = (int*)  alloc(512 * 4);
    (void)ws_size; (void)in_sizes; (void)n_in; (void)out_size;

    int nb = (n + 255) / 256;   // 391
    int eb = (e + 255) / 256;   // 6250

    k_init<<<nb, 256, 0, stream>>>(deg, cnt, fill, n);
    k_deg_cnt<<<eb, 256, 0, stream>>>(row, col, ew, deg, cnt, e);
    k_dinv<<<nb, 256, 0, stream>>>(deg, dinv, n);
    k_scan1<<<nb, 256, 0, stream>>>(cnt, rowptr, part, n);
    k_scan2<<<1, 512, 0, stream>>>(part, nb);
    k_scan3<<<nb, 256, 0, stream>>>(rowptr, part, n, e);
    k_fill<<<eb, 256, 0, stream>>>(row, col, ew, rowptr, fill, dinv, srcs, wn, e);

    int gb = n / 32;            // 3125 (exact)
    int ab = (n + 3) / 4;       // 25000

    // Layer 1: xw in d_out (scratch), h <- agg(relu)
    k_gemm<<<gb, 256, 0, stream>>>(x, W1, out);
    k_agg<<<ab, 256, 0, stream>>>(out, rowptr, srcs, wn, dinv, b1, h, 1, n);
    // Layer 2
    k_gemm<<<gb, 256, 0, stream>>>(h, W2, out);
    k_agg<<<ab, 256, 0, stream>>>(out, rowptr, srcs, wn, dinv, b2, h, 1, n);
    // Layer 3: in-place GEMM on h, aggregate into d_out (no relu)
    k_gemm<<<gb, 256, 0, stream>>>(h, W3, h);
    k_agg<<<ab, 256, 0, stream>>>(h, rowptr, srcs, wn, dinv, b3, out, 0, n);
}

// Round 2
// 720.780 us; speedup vs baseline: 1.3674x; 1.3674x over previous
//
#include <hip/hip_runtime.h>

#define NN 100000
#define NE 1600000

// ---------------- graph setup ----------------

__global__ __launch_bounds__(256) void k_init(float* deg, int* cnt, int* fill, int n) {
    int i = blockIdx.x * 256 + threadIdx.x;
    if (i < n) { deg[i] = 1.0f; cnt[i] = 0; fill[i] = 0; }   // 1.0 = self-loop weight
}

__global__ __launch_bounds__(256) void k_deg_cnt(const int* __restrict__ row,
                                                 const int* __restrict__ col,
                                                 const float* __restrict__ ew,
                                                 float* deg, int* cnt, int e) {
    int i = blockIdx.x * 256 + threadIdx.x;
    if (i < e) {
        int c = col[i];
        atomicAdd(&deg[c], ew[i]);
        atomicAdd(&cnt[c], 1);
    }
}

__global__ __launch_bounds__(256) void k_dinv(const float* __restrict__ deg, float* dinv, int n) {
    int i = blockIdx.x * 256 + threadIdx.x;
    if (i < n) { float d = deg[i]; dinv[i] = (d > 0.0f) ? rsqrtf(d) : 0.0f; }
}

// exclusive scan of cnt -> rowptr (3-phase)
__global__ __launch_bounds__(256) void k_scan1(const int* __restrict__ cnt,
                                               int* __restrict__ rowptr,
                                               int* __restrict__ part, int n) {
    __shared__ int s[256];
    int t = threadIdx.x;
    int i = blockIdx.x * 256 + t;
    int v = (i < n) ? cnt[i] : 0;
    s[t] = v;
    __syncthreads();
    for (int d = 1; d < 256; d <<= 1) {
        int y = (t >= d) ? s[t - d] : 0;
        __syncthreads();
        s[t] += y;
        __syncthreads();
    }
    if (i < n) rowptr[i] = s[t] - v;
    if (t == 255) part[blockIdx.x] = s[255];
}

__global__ __launch_bounds__(512) void k_scan2(int* part, int m) {
    __shared__ int s[512];
    int t = threadIdx.x;
    int v = (t < m) ? part[t] : 0;
    s[t] = v;
    __syncthreads();
    for (int d = 1; d < 512; d <<= 1) {
        int y = (t >= d) ? s[t - d] : 0;
        __syncthreads();
        s[t] += y;
        __syncthreads();
    }
    if (t < m) part[t] = s[t] - v;
}

__global__ __launch_bounds__(256) void k_scan3(int* rowptr, const int* __restrict__ part, int n, int e) {
    int i = blockIdx.x * 256 + threadIdx.x;
    if (i < n) rowptr[i] += part[blockIdx.x];
    if (i == 0) rowptr[n] = e;
}

// bucket-fill CSR by destination: srcs[p]=src node, wn[p]=dinv[src]*ew*dinv[dst]
__global__ __launch_bounds__(256) void k_fill(const int* __restrict__ row,
                                              const int* __restrict__ col,
                                              const float* __restrict__ ew,
                                              const int* __restrict__ rowptr,
                                              int* fill, const float* __restrict__ dinv,
                                              int* __restrict__ srcs, float* __restrict__ wn, int e) {
    int i = blockIdx.x * 256 + threadIdx.x;
    if (i < e) {
        int c = col[i];
        int r = row[i];
        int p = rowptr[c] + atomicAdd(&fill[c], 1);
        srcs[p] = r;
        wn[p] = dinv[r] * ew[i] * dinv[c];
    }
}

// ---------------- fp32 GEMM -> bf16 output ----------------
// C_bf16[nx128] = A_fp32[nx128] @ W_fp32[128x128]. 32 rows/block, W whole in LDS.
static __device__ __forceinline__ unsigned f2bf_rne(float f) {
    unsigned u = __float_as_uint(f);
    return (u + 0x7FFFu + ((u >> 16) & 1u)) >> 16;   // round-to-nearest-even
}

__global__ __launch_bounds__(256) void k_gemm(const float* __restrict__ A,
                                              const float* __restrict__ W,
                                              unsigned* __restrict__ Cb /* bf16 pairs */) {
    __shared__ float sW[128 * 128];
    __shared__ float sA[32 * 128];
    int t = threadIdx.x;
    size_t r0 = (size_t)blockIdx.x * 32;

    const float4* W4 = (const float4*)W;
    float4* sW4 = (float4*)sW;
#pragma unroll
    for (int i = 0; i < 16; ++i) sW4[t + 256 * i] = W4[t + 256 * i];

    const float4* A4 = (const float4*)(A + r0 * 128);
    float4* sA4 = (float4*)sA;
#pragma unroll
    for (int i = 0; i < 4; ++i) sA4[t + 256 * i] = A4[t + 256 * i];
    __syncthreads();

    int rr = (t >> 5) << 2;   // 0..28
    int cc = (t & 31) << 2;   // 0..124
    float acc[4][4] = {{0.0f}};

#pragma unroll 2
    for (int k = 0; k < 128; k += 4) {
        float4 w0 = *(const float4*)&sW[(k + 0) * 128 + cc];
        float4 w1 = *(const float4*)&sW[(k + 1) * 128 + cc];
        float4 w2 = *(const float4*)&sW[(k + 2) * 128 + cc];
        float4 w3 = *(const float4*)&sW[(k + 3) * 128 + cc];
#pragma unroll
        for (int i = 0; i < 4; ++i) {
            float4 a = *(const float4*)&sA[(rr + i) * 128 + k];
            acc[i][0] = fmaf(a.x, w0.x, acc[i][0]);
            acc[i][1] = fmaf(a.x, w0.y, acc[i][1]);
            acc[i][2] = fmaf(a.x, w0.z, acc[i][2]);
            acc[i][3] = fmaf(a.x, w0.w, acc[i][3]);
            acc[i][0] = fmaf(a.y, w1.x, acc[i][0]);
            acc[i][1] = fmaf(a.y, w1.y, acc[i][1]);
            acc[i][2] = fmaf(a.y, w1.z, acc[i][2]);
            acc[i][3] = fmaf(a.y, w1.w, acc[i][3]);
            acc[i][0] = fmaf(a.z, w2.x, acc[i][0]);
            acc[i][1] = fmaf(a.z, w2.y, acc[i][1]);
            acc[i][2] = fmaf(a.z, w2.z, acc[i][2]);
            acc[i][3] = fmaf(a.z, w2.w, acc[i][3]);
            acc[i][0] = fmaf(a.w, w3.x, acc[i][0]);
            acc[i][1] = fmaf(a.w, w3.y, acc[i][1]);
            acc[i][2] = fmaf(a.w, w3.z, acc[i][2]);
            acc[i][3] = fmaf(a.w, w3.w, acc[i][3]);
        }
    }

    // epilogue: pack 4 fp32 -> 4 bf16 (2 uints), store 8 B/thread/row
#pragma unroll
    for (int i = 0; i < 4; ++i) {
        unsigned lo = f2bf_rne(acc[i][0]) | (f2bf_rne(acc[i][1]) << 16);
        unsigned hi = f2bf_rne(acc[i][2]) | (f2bf_rne(acc[i][3]) << 16);
        uint2 o = make_uint2(lo, hi);
        *(uint2*)&Cb[((r0 + rr + i) * 128 + cc) >> 1] = o;
    }
}

// ---------------- pull-aggregation over bf16 rows ----------------
// One wave per node; lane owns channels [2*lane, 2*lane+1] = one uint (bf16 pair).
// Edge meta loaded coalesced in batches of 64 and broadcast via shuffle.
__global__ __launch_bounds__(256) void k_agg(const unsigned* __restrict__ XWb,
                                             const int* __restrict__ rowptr,
                                             const int* __restrict__ srcs,
                                             const float* __restrict__ wn,
                                             const float* __restrict__ dinv,
                                             const float* __restrict__ bias,
                                             float* __restrict__ out, int relu, int n) {
    int lane = threadIdx.x & 63;
    int node = blockIdx.x * 4 + (threadIdx.x >> 6);
    if (node >= n) return;

    float di = dinv[node];
    float selfw = di * di;   // dinv * 1.0 * dinv
    unsigned uself = XWb[(size_t)node * 64 + lane];
    float2 bv = *(const float2*)(bias + lane * 2);
    float ax = fmaf(selfw, __uint_as_float(uself << 16), bv.x);
    float ay = fmaf(selfw, __uint_as_float(uself & 0xFFFF0000u), bv.y);

    int p0 = rowptr[node], p1 = rowptr[node + 1];
    for (int base = p0; base < p1; base += 64) {
        int m = p1 - base; if (m > 64) m = 64;
        int idx = base + (lane < m ? lane : m - 1);
        int sv = srcs[idx];
        float wv = wn[idx];
        int j = 0;
        for (; j + 4 <= m; j += 4) {
            int s0 = __shfl(sv, j), s1 = __shfl(sv, j + 1);
            int s2 = __shfl(sv, j + 2), s3 = __shfl(sv, j + 3);
            float w0 = __shfl(wv, j), w1 = __shfl(wv, j + 1);
            float w2 = __shfl(wv, j + 2), w3 = __shfl(wv, j + 3);
            unsigned u0 = XWb[(size_t)s0 * 64 + lane];
            unsigned u1 = XWb[(size_t)s1 * 64 + lane];
            unsigned u2 = XWb[(size_t)s2 * 64 + lane];
            unsigned u3 = XWb[(size_t)s3 * 64 + lane];
            ax = fmaf(w0, __uint_as_float(u0 << 16), ax);
            ay = fmaf(w0, __uint_as_float(u0 & 0xFFFF0000u), ay);
            ax = fmaf(w1, __uint_as_float(u1 << 16), ax);
            ay = fmaf(w1, __uint_as_float(u1 & 0xFFFF0000u), ay);
            ax = fmaf(w2, __uint_as_float(u2 << 16), ax);
            ay = fmaf(w2, __uint_as_float(u2 & 0xFFFF0000u), ay);
            ax = fmaf(w3, __uint_as_float(u3 << 16), ax);
            ay = fmaf(w3, __uint_as_float(u3 & 0xFFFF0000u), ay);
        }
        for (; j < m; ++j) {
            int s = __shfl(sv, j);
            float w = __shfl(wv, j);
            unsigned u = XWb[(size_t)s * 64 + lane];
            ax = fmaf(w, __uint_as_float(u << 16), ax);
            ay = fmaf(w, __uint_as_float(u & 0xFFFF0000u), ay);
        }
    }
    if (relu) { ax = fmaxf(ax, 0.0f); ay = fmaxf(ay, 0.0f); }
    *(float2*)(out + (size_t)node * 128 + lane * 2) = make_float2(ax, ay);
}

// ---------------- launcher ----------------
extern "C" void kernel_launch(void* const* d_in, const int* in_sizes, int n_in,
                              void* d_out, int out_size, void* d_ws, size_t ws_size,
                              hipStream_t stream) {
    const float* x  = (const float*)d_in[0];
    const int*   ei = (const int*)d_in[1];
    const float* ew = (const float*)d_in[2];
    const float* W1 = (const float*)d_in[3];
    const float* b1 = (const float*)d_in[4];
    const float* W2 = (const float*)d_in[5];
    const float* b2 = (const float*)d_in[6];
    const float* W3 = (const float*)d_in[7];
    const float* b3 = (const float*)d_in[8];
    float* out = (float*)d_out;

    const int n = NN, e = NE;
    const int* row = ei;
    const int* col = ei + e;

    char* ws = (char*)d_ws;
    size_t off = 0;
    auto alloc = [&](size_t bytes) -> void* {
        void* p = ws + off;
        off = (off + bytes + 255) & ~(size_t)255;
        return p;
    };
    float*    h      = (float*)   alloc((size_t)n * 128 * 4);  // fp32 hidden
    unsigned* xwb    = (unsigned*)alloc((size_t)n * 128 * 2);  // bf16 xw (gather target)
    float*    deg    = (float*)   alloc((size_t)n * 4);
    float*    dinv   = (float*)   alloc((size_t)n * 4);
    int*      cnt    = (int*)     alloc((size_t)n * 4);
    int*      rowptr = (int*)     alloc((size_t)(n + 1) * 4);
    int*      fill   = (int*)     alloc((size_t)n * 4);
    int*      srcs   = (int*)     alloc((size_t)e * 4);
    float*    wn     = (float*)   alloc((size_t)e * 4);
    int*      part   = (int*)     alloc(512 * 4);
    (void)ws_size; (void)in_sizes; (void)n_in; (void)out_size;

    int nb = (n + 255) / 256;
    int eb = (e + 255) / 256;

    k_init<<<nb, 256, 0, stream>>>(deg, cnt, fill, n);
    k_deg_cnt<<<eb, 256, 0, stream>>>(row, col, ew, deg, cnt, e);
    k_dinv<<<nb, 256, 0, stream>>>(deg, dinv, n);
    k_scan1<<<nb, 256, 0, stream>>>(cnt, rowptr, part, n);
    k_scan2<<<1, 512, 0, stream>>>(part, nb);
    k_scan3<<<nb, 256, 0, stream>>>(rowptr, part, n, e);
    k_fill<<<eb, 256, 0, stream>>>(row, col, ew, rowptr, fill, dinv, srcs, wn, e);

    int gb = n / 32;       // 3125
    int ab = (n + 3) / 4;  // 25000

    // Layer 1
    k_gemm<<<gb, 256, 0, stream>>>(x, W1, xwb);
    k_agg<<<ab, 256, 0, stream>>>(xwb, rowptr, srcs, wn, dinv, b1, h, 1, n);
    // Layer 2
    k_gemm<<<gb, 256, 0, stream>>>(h, W2, xwb);
    k_agg<<<ab, 256, 0, stream>>>(xwb, rowptr, srcs, wn, dinv, b2, h, 1, n);
    // Layer 3 (no relu, fp32 out)
    k_gemm<<<gb, 256, 0, stream>>>(h, W3, xwb);
    k_agg<<<ab, 256, 0, stream>>>(xwb, rowptr, srcs, wn, dinv, b3, out, 0, n);
}

// Round 3
// 623.354 us; speedup vs baseline: 1.5811x; 1.1563x over previous
//
#include <hip/hip_runtime.h>

#define NN 100000
#define NE 1600000

// ---------------- graph setup ----------------
// packed[c]: high 40 bits = sum of ew (fixed point, 20 frac bits), low 24 = count.
// One 64-bit memory-side atomic per edge (vs 2x32-bit before); the returned old
// value's count field is this edge's rank within its destination bucket, which
// makes the CSR fill atomic-free.

__global__ __launch_bounds__(256) void k_init(unsigned long long* packed, int n) {
    int i = blockIdx.x * 256 + threadIdx.x;
    if (i < n) packed[i] = 0ull;
}

__global__ __launch_bounds__(256) void k_pass1(const int* __restrict__ col,
                                               const float* __restrict__ ew,
                                               unsigned long long* packed,
                                               int* __restrict__ rank, int e) {
    int i = blockIdx.x * 256 + threadIdx.x;
    if (i < e) {
        int c = col[i];
        unsigned fe = (unsigned)__float2uint_rn(ew[i] * 1048576.0f);  // 20 frac bits
        unsigned long long inc = ((unsigned long long)fe << 24) | 1ull;
        unsigned long long old = atomicAdd(&packed[c], inc);
        rank[i] = (int)(old & 0xFFFFFFull);
    }
}

__global__ __launch_bounds__(256) void k_dinv(const unsigned long long* __restrict__ packed,
                                              float* dinv, int n) {
    int i = blockIdx.x * 256 + threadIdx.x;
    if (i < n) {
        float deg = 1.0f + (float)(packed[i] >> 24) * (1.0f / 1048576.0f); // +1 self-loop
        dinv[i] = rsqrtf(deg);   // deg >= 1 always
    }
}

// exclusive scan of counts (low 24 bits of packed) -> rowptr
__global__ __launch_bounds__(256) void k_scan1(const unsigned long long* __restrict__ packed,
                                               int* __restrict__ rowptr,
                                               int* __restrict__ part, int n) {
    __shared__ int s[256];
    int t = threadIdx.x;
    int i = blockIdx.x * 256 + t;
    int v = (i < n) ? (int)(packed[i] & 0xFFFFFFull) : 0;
    s[t] = v;
    __syncthreads();
    for (int d = 1; d < 256; d <<= 1) {
        int y = (t >= d) ? s[t - d] : 0;
        __syncthreads();
        s[t] += y;
        __syncthreads();
    }
    if (i < n) rowptr[i] = s[t] - v;
    if (t == 255) part[blockIdx.x] = s[255];
}

__global__ __launch_bounds__(512) void k_scan2(int* part, int m) {
    __shared__ int s[512];
    int t = threadIdx.x;
    int v = (t < m) ? part[t] : 0;
    s[t] = v;
    __syncthreads();
    for (int d = 1; d < 512; d <<= 1) {
        int y = (t >= d) ? s[t - d] : 0;
        __syncthreads();
        s[t] += y;
        __syncthreads();
    }
    if (t < m) part[t] = s[t] - v;
}

__global__ __launch_bounds__(256) void k_scan3(int* rowptr, const int* __restrict__ part, int n, int e) {
    int i = blockIdx.x * 256 + threadIdx.x;
    if (i < n) rowptr[i] += part[blockIdx.x];
    if (i == 0) rowptr[n] = e;
}

// atomic-free CSR fill using precomputed ranks
__global__ __launch_bounds__(256) void k_fill(const int* __restrict__ row,
                                              const int* __restrict__ col,
                                              const float* __restrict__ ew,
                                              const int* __restrict__ rowptr,
                                              const int* __restrict__ rank,
                                              const float* __restrict__ dinv,
                                              int* __restrict__ srcs, float* __restrict__ wn, int e) {
    int i = blockIdx.x * 256 + threadIdx.x;
    if (i < e) {
        int c = col[i];
        int r = row[i];
        int p = rowptr[c] + rank[i];
        srcs[p] = r;
        wn[p] = dinv[r] * ew[i] * dinv[c];
    }
}

// ---------------- fp32 GEMM -> bf16 output ----------------
static __device__ __forceinline__ unsigned f2bf_rne(float f) {
    unsigned u = __float_as_uint(f);
    return (u + 0x7FFFu + ((u >> 16) & 1u)) >> 16;   // round-to-nearest-even
}

__global__ __launch_bounds__(256) void k_gemm(const float* __restrict__ A,
                                              const float* __restrict__ W,
                                              unsigned* __restrict__ Cb /* bf16 pairs */) {
    __shared__ float sW[128 * 128];
    __shared__ float sA[32 * 128];
    int t = threadIdx.x;
    size_t r0 = (size_t)blockIdx.x * 32;

    const float4* W4 = (const float4*)W;
    float4* sW4 = (float4*)sW;
#pragma unroll
    for (int i = 0; i < 16; ++i) sW4[t + 256 * i] = W4[t + 256 * i];

    const float4* A4 = (const float4*)(A + r0 * 128);
    float4* sA4 = (float4*)sA;
#pragma unroll
    for (int i = 0; i < 4; ++i) sA4[t + 256 * i] = A4[t + 256 * i];
    __syncthreads();

    int rr = (t >> 5) << 2;
    int cc = (t & 31) << 2;
    float acc[4][4] = {{0.0f}};

#pragma unroll 2
    for (int k = 0; k < 128; k += 4) {
        float4 w0 = *(const float4*)&sW[(k + 0) * 128 + cc];
        float4 w1 = *(const float4*)&sW[(k + 1) * 128 + cc];
        float4 w2 = *(const float4*)&sW[(k + 2) * 128 + cc];
        float4 w3 = *(const float4*)&sW[(k + 3) * 128 + cc];
#pragma unroll
        for (int i = 0; i < 4; ++i) {
            float4 a = *(const float4*)&sA[(rr + i) * 128 + k];
            acc[i][0] = fmaf(a.x, w0.x, acc[i][0]);
            acc[i][1] = fmaf(a.x, w0.y, acc[i][1]);
            acc[i][2] = fmaf(a.x, w0.z, acc[i][2]);
            acc[i][3] = fmaf(a.x, w0.w, acc[i][3]);
            acc[i][0] = fmaf(a.y, w1.x, acc[i][0]);
            acc[i][1] = fmaf(a.y, w1.y, acc[i][1]);
            acc[i][2] = fmaf(a.y, w1.z, acc[i][2]);
            acc[i][3] = fmaf(a.y, w1.w, acc[i][3]);
            acc[i][0] = fmaf(a.z, w2.x, acc[i][0]);
            acc[i][1] = fmaf(a.z, w2.y, acc[i][1]);
            acc[i][2] = fmaf(a.z, w2.z, acc[i][2]);
            acc[i][3] = fmaf(a.z, w2.w, acc[i][3]);
            acc[i][0] = fmaf(a.w, w3.x, acc[i][0]);
            acc[i][1] = fmaf(a.w, w3.y, acc[i][1]);
            acc[i][2] = fmaf(a.w, w3.z, acc[i][2]);
            acc[i][3] = fmaf(a.w, w3.w, acc[i][3]);
        }
    }

#pragma unroll
    for (int i = 0; i < 4; ++i) {
        unsigned lo = f2bf_rne(acc[i][0]) | (f2bf_rne(acc[i][1]) << 16);
        unsigned hi = f2bf_rne(acc[i][2]) | (f2bf_rne(acc[i][3]) << 16);
        uint2 o = make_uint2(lo, hi);
        *(uint2*)&Cb[((r0 + rr + i) * 128 + cc) >> 1] = o;
    }
}

// ---------------- pull-aggregation over bf16 rows ----------------
__global__ __launch_bounds__(256) void k_agg(const unsigned* __restrict__ XWb,
                                             const int* __restrict__ rowptr,
                                             const int* __restrict__ srcs,
                                             const float* __restrict__ wn,
                                             const float* __restrict__ dinv,
                                             const float* __restrict__ bias,
                                             float* __restrict__ out, int relu, int n) {
    int lane = threadIdx.x & 63;
    int node = blockIdx.x * 4 + (threadIdx.x >> 6);
    if (node >= n) return;

    float di = dinv[node];
    float selfw = di * di;
    unsigned uself = XWb[(size_t)node * 64 + lane];
    float2 bv = *(const float2*)(bias + lane * 2);
    float ax = fmaf(selfw, __uint_as_float(uself << 16), bv.x);
    float ay = fmaf(selfw, __uint_as_float(uself & 0xFFFF0000u), bv.y);

    int p0 = rowptr[node], p1 = rowptr[node + 1];
    for (int base = p0; base < p1; base += 64) {
        int m = p1 - base; if (m > 64) m = 64;
        int idx = base + (lane < m ? lane : m - 1);
        int sv = srcs[idx];
        float wv = wn[idx];
        int j = 0;
        for (; j + 4 <= m; j += 4) {
            int s0 = __shfl(sv, j), s1 = __shfl(sv, j + 1);
            int s2 = __shfl(sv, j + 2), s3 = __shfl(sv, j + 3);
            float w0 = __shfl(wv, j), w1 = __shfl(wv, j + 1);
            float w2 = __shfl(wv, j + 2), w3 = __shfl(wv, j + 3);
            unsigned u0 = XWb[(size_t)s0 * 64 + lane];
            unsigned u1 = XWb[(size_t)s1 * 64 + lane];
            unsigned u2 = XWb[(size_t)s2 * 64 + lane];
            unsigned u3 = XWb[(size_t)s3 * 64 + lane];
            ax = fmaf(w0, __uint_as_float(u0 << 16), ax);
            ay = fmaf(w0, __uint_as_float(u0 & 0xFFFF0000u), ay);
            ax = fmaf(w1, __uint_as_float(u1 << 16), ax);
            ay = fmaf(w1, __uint_as_float(u1 & 0xFFFF0000u), ay);
            ax = fmaf(w2, __uint_as_float(u2 << 16), ax);
            ay = fmaf(w2, __uint_as_float(u2 & 0xFFFF0000u), ay);
            ax = fmaf(w3, __uint_as_float(u3 << 16), ax);
            ay = fmaf(w3, __uint_as_float(u3 & 0xFFFF0000u), ay);
        }
        for (; j < m; ++j) {
            int s = __shfl(sv, j);
            float w = __shfl(wv, j);
            unsigned u = XWb[(size_t)s * 64 + lane];
            ax = fmaf(w, __uint_as_float(u << 16), ax);
            ay = fmaf(w, __uint_as_float(u & 0xFFFF0000u), ay);
        }
    }
    if (relu) { ax = fmaxf(ax, 0.0f); ay = fmaxf(ay, 0.0f); }
    *(float2*)(out + (size_t)node * 128 + lane * 2) = make_float2(ax, ay);
}

// ---------------- launcher ----------------
extern "C" void kernel_launch(void* const* d_in, const int* in_sizes, int n_in,
                              void* d_out, int out_size, void* d_ws, size_t ws_size,
                              hipStream_t stream) {
    const float* x  = (const float*)d_in[0];
    const int*   ei = (const int*)d_in[1];
    const float* ew = (const float*)d_in[2];
    const float* W1 = (const float*)d_in[3];
    const float* b1 = (const float*)d_in[4];
    const float* W2 = (const float*)d_in[5];
    const float* b2 = (const float*)d_in[6];
    const float* W3 = (const float*)d_in[7];
    const float* b3 = (const float*)d_in[8];
    float* out = (float*)d_out;

    const int n = NN, e = NE;
    const int* row = ei;
    const int* col = ei + e;

    char* ws = (char*)d_ws;
    size_t off = 0;
    auto alloc = [&](size_t bytes) -> void* {
        void* p = ws + off;
        off = (off + bytes + 255) & ~(size_t)255;
        return p;
    };
    float*              h      = (float*)             alloc((size_t)n * 128 * 4);
    unsigned*           xwb    = (unsigned*)          alloc((size_t)n * 128 * 2);
    unsigned long long* packed = (unsigned long long*)alloc((size_t)n * 8);
    float*              dinv   = (float*)             alloc((size_t)n * 4);
    int*                rowptr = (int*)               alloc((size_t)(n + 1) * 4);
    int*                rank   = (int*)               alloc((size_t)e * 4);
    int*                srcs   = (int*)               alloc((size_t)e * 4);
    float*              wn     = (float*)             alloc((size_t)e * 4);
    int*                part   = (int*)               alloc(512 * 4);
    (void)ws_size; (void)in_sizes; (void)n_in; (void)out_size;

    int nb = (n + 255) / 256;   // 391
    int eb = (e + 255) / 256;   // 6250

    k_init<<<nb, 256, 0, stream>>>(packed, n);
    k_pass1<<<eb, 256, 0, stream>>>(col, ew, packed, rank, e);
    k_dinv<<<nb, 256, 0, stream>>>(packed, dinv, n);
    k_scan1<<<nb, 256, 0, stream>>>(packed, rowptr, part, n);
    k_scan2<<<1, 512, 0, stream>>>(part, nb);
    k_scan3<<<nb, 256, 0, stream>>>(rowptr, part, n, e);
    k_fill<<<eb, 256, 0, stream>>>(row, col, ew, rowptr, rank, dinv, srcs, wn, e);

    int gb = n / 32;       // 3125
    int ab = (n + 3) / 4;  // 25000

    // Layer 1
    k_gemm<<<gb, 256, 0, stream>>>(x, W1, xwb);
    k_agg<<<ab, 256, 0, stream>>>(xwb, rowptr, srcs, wn, dinv, b1, h, 1, n);
    // Layer 2
    k_gemm<<<gb, 256, 0, stream>>>(h, W2, xwb);
    k_agg<<<ab, 256, 0, stream>>>(xwb, rowptr, srcs, wn, dinv, b2, h, 1, n);
    // Layer 3 (no relu, fp32 out)
    k_gemm<<<gb, 256, 0, stream>>>(h, W3, xwb);
    k_agg<<<ab, 256, 0, stream>>>(xwb, rowptr, srcs, wn, dinv, b3, out, 0, n);
}

// Round 4
// 588.739 us; speedup vs baseline: 1.6741x; 1.0588x over previous
//
#include <hip/hip_runtime.h>

#define NN 100000
#define NE 1600000

// ---------------- graph setup ----------------
// packed[c]: high 40 bits = sum of ew (fixed point, 20 frac bits), low 24 = count.
// Single 64-bit memory-side atomic per edge; returned count field = edge's rank
// within its destination bucket -> atomic-free CSR fill.

__global__ __launch_bounds__(256) void k_init(unsigned long long* packed, int n) {
    int i = blockIdx.x * 256 + threadIdx.x;
    if (i < n) packed[i] = 0ull;
}

__global__ __launch_bounds__(256) void k_pass1(const int* __restrict__ col,
                                               const float* __restrict__ ew,
                                               unsigned long long* packed,
                                               int* __restrict__ rank, int e) {
    int i = blockIdx.x * 256 + threadIdx.x;
    if (i < e) {
        int c = col[i];
        unsigned fe = (unsigned)__float2uint_rn(ew[i] * 1048576.0f);  // 20 frac bits
        unsigned long long inc = ((unsigned long long)fe << 24) | 1ull;
        unsigned long long old = atomicAdd(&packed[c], inc);
        rank[i] = (int)(old & 0xFFFFFFull);
    }
}

// fused: exclusive scan of counts -> rowptr, plus dinv = rsqrt(deg)
__global__ __launch_bounds__(256) void k_scan1(const unsigned long long* __restrict__ packed,
                                               int* __restrict__ rowptr,
                                               int* __restrict__ part,
                                               float* __restrict__ dinv, int n) {
    __shared__ int s[256];
    int t = threadIdx.x;
    int i = blockIdx.x * 256 + t;
    unsigned long long pk = (i < n) ? packed[i] : 0ull;
    int v = (int)(pk & 0xFFFFFFull);
    if (i < n) {
        float deg = 1.0f + (float)(pk >> 24) * (1.0f / 1048576.0f);  // +1 self-loop
        dinv[i] = rsqrtf(deg);   // deg >= 1 always
    }
    s[t] = v;
    __syncthreads();
    for (int d = 1; d < 256; d <<= 1) {
        int y = (t >= d) ? s[t - d] : 0;
        __syncthreads();
        s[t] += y;
        __syncthreads();
    }
    if (i < n) rowptr[i] = s[t] - v;
    if (t == 255) part[blockIdx.x] = s[255];
}

__global__ __launch_bounds__(512) void k_scan2(int* part, int m) {
    __shared__ int s[512];
    int t = threadIdx.x;
    int v = (t < m) ? part[t] : 0;
    s[t] = v;
    __syncthreads();
    for (int d = 1; d < 512; d <<= 1) {
        int y = (t >= d) ? s[t - d] : 0;
        __syncthreads();
        s[t] += y;
        __syncthreads();
    }
    if (t < m) part[t] = s[t] - v;
}

__global__ __launch_bounds__(256) void k_scan3(int* rowptr, const int* __restrict__ part, int n, int e) {
    int i = blockIdx.x * 256 + threadIdx.x;
    if (i < n) rowptr[i] += part[blockIdx.x];
    if (i == 0) rowptr[n] = e;
}

// atomic-free CSR fill; (src, wn) packed -> ONE 8-byte scattered store per edge
__global__ __launch_bounds__(256) void k_fill(const int* __restrict__ row,
                                              const int* __restrict__ col,
                                              const float* __restrict__ ew,
                                              const int* __restrict__ rowptr,
                                              const int* __restrict__ rank,
                                              const float* __restrict__ dinv,
                                              uint2* __restrict__ meta, int e) {
    int i = blockIdx.x * 256 + threadIdx.x;
    if (i < e) {
        int c = col[i];
        int r = row[i];
        int p = rowptr[c] + rank[i];
        float w = dinv[r] * ew[i] * dinv[c];
        meta[p] = make_uint2((unsigned)r, __float_as_uint(w));
    }
}

// ---------------- fp32 GEMM -> bf16 output ----------------
static __device__ __forceinline__ unsigned f2bf_rne(float f) {
    unsigned u = __float_as_uint(f);
    return (u + 0x7FFFu + ((u >> 16) & 1u)) >> 16;   // round-to-nearest-even
}

__global__ __launch_bounds__(256) void k_gemm(const float* __restrict__ A,
                                              const float* __restrict__ W,
                                              unsigned* __restrict__ Cb /* bf16 pairs */) {
    __shared__ float sW[128 * 128];
    __shared__ float sA[32 * 128];
    int t = threadIdx.x;
    size_t r0 = (size_t)blockIdx.x * 32;

    const float4* W4 = (const float4*)W;
    float4* sW4 = (float4*)sW;
#pragma unroll
    for (int i = 0; i < 16; ++i) sW4[t + 256 * i] = W4[t + 256 * i];

    const float4* A4 = (const float4*)(A + r0 * 128);
    float4* sA4 = (float4*)sA;
#pragma unroll
    for (int i = 0; i < 4; ++i) sA4[t + 256 * i] = A4[t + 256 * i];
    __syncthreads();

    int rr = (t >> 5) << 2;
    int cc = (t & 31) << 2;
    float acc[4][4] = {{0.0f}};

#pragma unroll 2
    for (int k = 0; k < 128; k += 4) {
        float4 w0 = *(const float4*)&sW[(k + 0) * 128 + cc];
        float4 w1 = *(const float4*)&sW[(k + 1) * 128 + cc];
        float4 w2 = *(const float4*)&sW[(k + 2) * 128 + cc];
        float4 w3 = *(const float4*)&sW[(k + 3) * 128 + cc];
#pragma unroll
        for (int i = 0; i < 4; ++i) {
            float4 a = *(const float4*)&sA[(rr + i) * 128 + k];
            acc[i][0] = fmaf(a.x, w0.x, acc[i][0]);
            acc[i][1] = fmaf(a.x, w0.y, acc[i][1]);
            acc[i][2] = fmaf(a.x, w0.z, acc[i][2]);
            acc[i][3] = fmaf(a.x, w0.w, acc[i][3]);
            acc[i][0] = fmaf(a.y, w1.x, acc[i][0]);
            acc[i][1] = fmaf(a.y, w1.y, acc[i][1]);
            acc[i][2] = fmaf(a.y, w1.z, acc[i][2]);
            acc[i][3] = fmaf(a.y, w1.w, acc[i][3]);
            acc[i][0] = fmaf(a.z, w2.x, acc[i][0]);
            acc[i][1] = fmaf(a.z, w2.y, acc[i][1]);
            acc[i][2] = fmaf(a.z, w2.z, acc[i][2]);
            acc[i][3] = fmaf(a.z, w2.w, acc[i][3]);
            acc[i][0] = fmaf(a.w, w3.x, acc[i][0]);
            acc[i][1] = fmaf(a.w, w3.y, acc[i][1]);
            acc[i][2] = fmaf(a.w, w3.z, acc[i][2]);
            acc[i][3] = fmaf(a.w, w3.w, acc[i][3]);
        }
    }

#pragma unroll
    for (int i = 0; i < 4; ++i) {
        unsigned lo = f2bf_rne(acc[i][0]) | (f2bf_rne(acc[i][1]) << 16);
        unsigned hi = f2bf_rne(acc[i][2]) | (f2bf_rne(acc[i][3]) << 16);
        uint2 o = make_uint2(lo, hi);
        *(uint2*)&Cb[((r0 + rr + i) * 128 + cc) >> 1] = o;
    }
}

// ---------------- pull-aggregation over bf16 rows ----------------
__global__ __launch_bounds__(256) void k_agg(const unsigned* __restrict__ XWb,
                                             const int* __restrict__ rowptr,
                                             const uint2* __restrict__ meta,
                                             const float* __restrict__ dinv,
                                             const float* __restrict__ bias,
                                             float* __restrict__ out, int relu, int n) {
    int lane = threadIdx.x & 63;
    int node = blockIdx.x * 4 + (threadIdx.x >> 6);
    if (node >= n) return;

    float di = dinv[node];
    float selfw = di * di;
    unsigned uself = XWb[(size_t)node * 64 + lane];
    float2 bv = *(const float2*)(bias + lane * 2);
    float ax = fmaf(selfw, __uint_as_float(uself << 16), bv.x);
    float ay = fmaf(selfw, __uint_as_float(uself & 0xFFFF0000u), bv.y);

    int p0 = rowptr[node], p1 = rowptr[node + 1];
    for (int base = p0; base < p1; base += 64) {
        int m = p1 - base; if (m > 64) m = 64;
        int idx = base + (lane < m ? lane : m - 1);
        uint2 mv = meta[idx];
        int sv = (int)mv.x;
        float wv = __uint_as_float(mv.y);
        int j = 0;
        for (; j + 4 <= m; j += 4) {
            int s0 = __shfl(sv, j), s1 = __shfl(sv, j + 1);
            int s2 = __shfl(sv, j + 2), s3 = __shfl(sv, j + 3);
            float w0 = __shfl(wv, j), w1 = __shfl(wv, j + 1);
            float w2 = __shfl(wv, j + 2), w3 = __shfl(wv, j + 3);
            unsigned u0 = XWb[(size_t)s0 * 64 + lane];
            unsigned u1 = XWb[(size_t)s1 * 64 + lane];
            unsigned u2 = XWb[(size_t)s2 * 64 + lane];
            unsigned u3 = XWb[(size_t)s3 * 64 + lane];
            ax = fmaf(w0, __uint_as_float(u0 << 16), ax);
            ay = fmaf(w0, __uint_as_float(u0 & 0xFFFF0000u), ay);
            ax = fmaf(w1, __uint_as_float(u1 << 16), ax);
            ay = fmaf(w1, __uint_as_float(u1 & 0xFFFF0000u), ay);
            ax = fmaf(w2, __uint_as_float(u2 << 16), ax);
            ay = fmaf(w2, __uint_as_float(u2 & 0xFFFF0000u), ay);
            ax = fmaf(w3, __uint_as_float(u3 << 16), ax);
            ay = fmaf(w3, __uint_as_float(u3 & 0xFFFF0000u), ay);
        }
        for (; j < m; ++j) {
            int s = __shfl(sv, j);
            float w = __shfl(wv, j);
            unsigned u = XWb[(size_t)s * 64 + lane];
            ax = fmaf(w, __uint_as_float(u << 16), ax);
            ay = fmaf(w, __uint_as_float(u & 0xFFFF0000u), ay);
        }
    }
    if (relu) { ax = fmaxf(ax, 0.0f); ay = fmaxf(ay, 0.0f); }
    *(float2*)(out + (size_t)node * 128 + lane * 2) = make_float2(ax, ay);
}

// ---------------- launcher ----------------
extern "C" void kernel_launch(void* const* d_in, const int* in_sizes, int n_in,
                              void* d_out, int out_size, void* d_ws, size_t ws_size,
                              hipStream_t stream) {
    const float* x  = (const float*)d_in[0];
    const int*   ei = (const int*)d_in[1];
    const float* ew = (const float*)d_in[2];
    const float* W1 = (const float*)d_in[3];
    const float* b1 = (const float*)d_in[4];
    const float* W2 = (const float*)d_in[5];
    const float* b2 = (const float*)d_in[6];
    const float* W3 = (const float*)d_in[7];
    const float* b3 = (const float*)d_in[8];
    float* out = (float*)d_out;

    const int n = NN, e = NE;
    const int* row = ei;
    const int* col = ei + e;

    char* ws = (char*)d_ws;
    size_t off = 0;
    auto alloc = [&](size_t bytes) -> void* {
        void* p = ws + off;
        off = (off + bytes + 255) & ~(size_t)255;
        return p;
    };
    float*              h      = (float*)             alloc((size_t)n * 128 * 4);
    unsigned*           xwb    = (unsigned*)          alloc((size_t)n * 128 * 2);
    unsigned long long* packed = (unsigned long long*)alloc((size_t)n * 8);
    float*              dinv   = (float*)             alloc((size_t)n * 4);
    int*                rowptr = (int*)               alloc((size_t)(n + 1) * 4);
    int*                rank   = (int*)               alloc((size_t)e * 4);
    uint2*              meta   = (uint2*)             alloc((size_t)e * 8);
    int*                part   = (int*)               alloc(512 * 4);
    (void)ws_size; (void)in_sizes; (void)n_in; (void)out_size;

    int nb = (n + 255) / 256;   // 391
    int eb = (e + 255) / 256;   // 6250

    k_init<<<nb, 256, 0, stream>>>(packed, n);
    k_pass1<<<eb, 256, 0, stream>>>(col, ew, packed, rank, e);
    k_scan1<<<nb, 256, 0, stream>>>(packed, rowptr, part, dinv, n);
    k_scan2<<<1, 512, 0, stream>>>(part, nb);
    k_scan3<<<nb, 256, 0, stream>>>(rowptr, part, n, e);
    k_fill<<<eb, 256, 0, stream>>>(row, col, ew, rowptr, rank, dinv, meta, e);

    int gb = n / 32;       // 3125
    int ab = (n + 3) / 4;  // 25000

    // Layer 1
    k_gemm<<<gb, 256, 0, stream>>>(x, W1, xwb);
    k_agg<<<ab, 256, 0, stream>>>(xwb, rowptr, meta, dinv, b1, h, 1, n);
    // Layer 2
    k_gemm<<<gb, 256, 0, stream>>>(h, W2, xwb);
    k_agg<<<ab, 256, 0, stream>>>(xwb, rowptr, meta, dinv, b2, h, 1, n);
    // Layer 3 (no relu, fp32 out)
    k_gemm<<<gb, 256, 0, stream>>>(h, W3, xwb);
    k_agg<<<ab, 256, 0, stream>>>(xwb, rowptr, meta, dinv, b3, out, 0, n);
}

// Round 5
// 545.153 us; speedup vs baseline: 1.8080x; 1.0800x over previous
//
#include <hip/hip_runtime.h>

#define NN 100000
#define NE 1600000

// bf16 helpers
static __device__ __forceinline__ unsigned f2bf_rne(float f) {
    unsigned u = __float_as_uint(f);
    return (u + 0x7FFFu + ((u >> 16) & 1u)) >> 16;   // round-to-nearest-even
}
static __device__ __forceinline__ float bf_lo(unsigned u) { return __uint_as_float(u << 16); }
static __device__ __forceinline__ float bf_hi(unsigned u) { return __uint_as_float(u & 0xFFFF0000u); }

// ---------------- graph setup ----------------
// packed[c]: high 40 bits = sum of ew (20-bit fixed point), low 24 = count.
// One memory-side 64-bit atomic per edge; returned count = edge's rank in its
// destination bucket -> atomic-free CSR fill.

__global__ __launch_bounds__(256) void k_init(unsigned long long* packed, int n) {
    int i = blockIdx.x * 256 + threadIdx.x;
    if (i < n) packed[i] = 0ull;
}

// ---------------- fused: layer-1 GEMM (fp32 A) || edge histogram pass ----------------
// 9375 blocks = 3125 GEMM (b%3==0) + 6250 pass1 (b%3!=0), interleaved so both kinds
// co-reside: GEMM is VALU/LDS-bound, pass1 is memory-side-atomic-bound -> overlap.
__global__ __launch_bounds__(256) void k_gp(const float* __restrict__ A,
                                            const float* __restrict__ W,
                                            unsigned* __restrict__ Cb,
                                            const int* __restrict__ col,
                                            const float* __restrict__ ew,
                                            unsigned long long* packed,
                                            int* __restrict__ rank, int e) {
    __shared__ float sW[128 * 128];
    __shared__ float sA[32 * 128];
    int b = blockIdx.x;
    int sub = b % 3;
    int q = b / 3;
    int t = threadIdx.x;

    if (sub != 0) {
        // ---- pass1: one edge per thread, single packed atomic ----
        int p = q * 2 + sub - 1;            // 0..6249
        int i = p * 256 + t;
        if (i < e) {
            int c = col[i];
            unsigned fe = (unsigned)__float2uint_rn(ew[i] * 1048576.0f);  // 20 frac bits
            unsigned long long inc = ((unsigned long long)fe << 24) | 1ull;
            unsigned long long old = atomicAdd(&packed[c], inc);
            rank[i] = (int)(old & 0xFFFFFFull);
        }
        return;
    }

    // ---- GEMM: rows [q*32, q*32+32), fp32 A, bf16 out ----
    size_t r0 = (size_t)q * 32;

    const float4* W4 = (const float4*)W;
    float4* sW4 = (float4*)sW;
#pragma unroll
    for (int i = 0; i < 16; ++i) sW4[t + 256 * i] = W4[t + 256 * i];

    const float4* A4 = (const float4*)(A + r0 * 128);
    float4* sA4 = (float4*)sA;
#pragma unroll
    for (int i = 0; i < 4; ++i) sA4[t + 256 * i] = A4[t + 256 * i];
    __syncthreads();

    int rr = (t >> 5) << 2;
    int cc = (t & 31) << 2;
    float acc[4][4] = {{0.0f}};

#pragma unroll 2
    for (int k = 0; k < 128; k += 4) {
        float4 w0 = *(const float4*)&sW[(k + 0) * 128 + cc];
        float4 w1 = *(const float4*)&sW[(k + 1) * 128 + cc];
        float4 w2 = *(const float4*)&sW[(k + 2) * 128 + cc];
        float4 w3 = *(const float4*)&sW[(k + 3) * 128 + cc];
#pragma unroll
        for (int i = 0; i < 4; ++i) {
            float4 a = *(const float4*)&sA[(rr + i) * 128 + k];
            acc[i][0] = fmaf(a.x, w0.x, acc[i][0]);
            acc[i][1] = fmaf(a.x, w0.y, acc[i][1]);
            acc[i][2] = fmaf(a.x, w0.z, acc[i][2]);
            acc[i][3] = fmaf(a.x, w0.w, acc[i][3]);
            acc[i][0] = fmaf(a.y, w1.x, acc[i][0]);
            acc[i][1] = fmaf(a.y, w1.y, acc[i][1]);
            acc[i][2] = fmaf(a.y, w1.z, acc[i][2]);
            acc[i][3] = fmaf(a.y, w1.w, acc[i][3]);
            acc[i][0] = fmaf(a.z, w2.x, acc[i][0]);
            acc[i][1] = fmaf(a.z, w2.y, acc[i][1]);
            acc[i][2] = fmaf(a.z, w2.z, acc[i][2]);
            acc[i][3] = fmaf(a.z, w2.w, acc[i][3]);
            acc[i][0] = fmaf(a.w, w3.x, acc[i][0]);
            acc[i][1] = fmaf(a.w, w3.y, acc[i][1]);
            acc[i][2] = fmaf(a.w, w3.z, acc[i][2]);
            acc[i][3] = fmaf(a.w, w3.w, acc[i][3]);
        }
    }

#pragma unroll
    for (int i = 0; i < 4; ++i) {
        unsigned lo = f2bf_rne(acc[i][0]) | (f2bf_rne(acc[i][1]) << 16);
        unsigned hi = f2bf_rne(acc[i][2]) | (f2bf_rne(acc[i][3]) << 16);
        *(uint2*)&Cb[((r0 + rr + i) * 128 + cc) >> 1] = make_uint2(lo, hi);
    }
}

// fused: exclusive scan of counts -> rowptr, plus dinv = rsqrt(deg)
__global__ __launch_bounds__(256) void k_scan1(const unsigned long long* __restrict__ packed,
                                               int* __restrict__ rowptr,
                                               int* __restrict__ part,
                                               float* __restrict__ dinv, int n) {
    __shared__ int s[256];
    int t = threadIdx.x;
    int i = blockIdx.x * 256 + t;
    unsigned long long pk = (i < n) ? packed[i] : 0ull;
    int v = (int)(pk & 0xFFFFFFull);
    if (i < n) {
        float deg = 1.0f + (float)(pk >> 24) * (1.0f / 1048576.0f);  // +1 self-loop
        dinv[i] = rsqrtf(deg);
    }
    s[t] = v;
    __syncthreads();
    for (int d = 1; d < 256; d <<= 1) {
        int y = (t >= d) ? s[t - d] : 0;
        __syncthreads();
        s[t] += y;
        __syncthreads();
    }
    if (i < n) rowptr[i] = s[t] - v;
    if (t == 255) part[blockIdx.x] = s[255];
}

__global__ __launch_bounds__(512) void k_scan2(int* part, int m) {
    __shared__ int s[512];
    int t = threadIdx.x;
    int v = (t < m) ? part[t] : 0;
    s[t] = v;
    __syncthreads();
    for (int d = 1; d < 512; d <<= 1) {
        int y = (t >= d) ? s[t - d] : 0;
        __syncthreads();
        s[t] += y;
        __syncthreads();
    }
    if (t < m) part[t] = s[t] - v;
}

__global__ __launch_bounds__(256) void k_scan3(int* rowptr, const int* __restrict__ part, int n, int e) {
    int i = blockIdx.x * 256 + threadIdx.x;
    if (i < n) rowptr[i] += part[blockIdx.x];
    if (i == 0) rowptr[n] = e;
}

// atomic-free CSR fill; (src, wn) packed -> ONE 8-byte scattered store per edge
__global__ __launch_bounds__(256) void k_fill(const int* __restrict__ row,
                                              const int* __restrict__ col,
                                              const float* __restrict__ ew,
                                              const int* __restrict__ rowptr,
                                              const int* __restrict__ rank,
                                              const float* __restrict__ dinv,
                                              uint2* __restrict__ meta, int e) {
    int i = blockIdx.x * 256 + threadIdx.x;
    if (i < e) {
        int c = col[i];
        int r = row[i];
        int p = rowptr[c] + rank[i];
        float w = dinv[r] * ew[i] * dinv[c];
        meta[p] = make_uint2((unsigned)r, __float_as_uint(w));
    }
}

// ---------------- GEMM with bf16 A (layers 2,3) -> bf16 out ----------------
__global__ __launch_bounds__(256) void k_gemm_b(const unsigned* __restrict__ Ab,
                                                const float* __restrict__ W,
                                                unsigned* __restrict__ Cb) {
    __shared__ float sW[128 * 128];
    __shared__ float sA[32 * 128];
    int t = threadIdx.x;
    size_t r0 = (size_t)blockIdx.x * 32;

    const float4* W4 = (const float4*)W;
    float4* sW4 = (float4*)sW;
#pragma unroll
    for (int i = 0; i < 16; ++i) sW4[t + 256 * i] = W4[t + 256 * i];

    // A tile: 32 rows x 64 uints (bf16 pairs) = 1024 uint2; convert to fp32 in LDS
    const uint2* A2 = (const uint2*)(Ab + r0 * 64);
#pragma unroll
    for (int i = 0; i < 4; ++i) {
        int j = t + 256 * i;        // uint2 index, 4 fp32 elements at 4*j
        uint2 u = A2[j];
        float4 f = make_float4(bf_lo(u.x), bf_hi(u.x), bf_lo(u.y), bf_hi(u.y));
        *(float4*)&sA[4 * j] = f;
    }
    __syncthreads();

    int rr = (t >> 5) << 2;
    int cc = (t & 31) << 2;
    float acc[4][4] = {{0.0f}};

#pragma unroll 2
    for (int k = 0; k < 128; k += 4) {
        float4 w0 = *(const float4*)&sW[(k + 0) * 128 + cc];
        float4 w1 = *(const float4*)&sW[(k + 1) * 128 + cc];
        float4 w2 = *(const float4*)&sW[(k + 2) * 128 + cc];
        float4 w3 = *(const float4*)&sW[(k + 3) * 128 + cc];
#pragma unroll
        for (int i = 0; i < 4; ++i) {
            float4 a = *(const float4*)&sA[(rr + i) * 128 + k];
            acc[i][0] = fmaf(a.x, w0.x, acc[i][0]);
            acc[i][1] = fmaf(a.x, w0.y, acc[i][1]);
            acc[i][2] = fmaf(a.x, w0.z, acc[i][2]);
            acc[i][3] = fmaf(a.x, w0.w, acc[i][3]);
            acc[i][0] = fmaf(a.y, w1.x, acc[i][0]);
            acc[i][1] = fmaf(a.y, w1.y, acc[i][1]);
            acc[i][2] = fmaf(a.y, w1.z, acc[i][2]);
            acc[i][3] = fmaf(a.y, w1.w, acc[i][3]);
            acc[i][0] = fmaf(a.z, w2.x, acc[i][0]);
            acc[i][1] = fmaf(a.z, w2.y, acc[i][1]);
            acc[i][2] = fmaf(a.z, w2.z, acc[i][2]);
            acc[i][3] = fmaf(a.z, w2.w, acc[i][3]);
            acc[i][0] = fmaf(a.w, w3.x, acc[i][0]);
            acc[i][1] = fmaf(a.w, w3.y, acc[i][1]);
            acc[i][2] = fmaf(a.w, w3.z, acc[i][2]);
            acc[i][3] = fmaf(a.w, w3.w, acc[i][3]);
        }
    }

#pragma unroll
    for (int i = 0; i < 4; ++i) {
        unsigned lo = f2bf_rne(acc[i][0]) | (f2bf_rne(acc[i][1]) << 16);
        unsigned hi = f2bf_rne(acc[i][2]) | (f2bf_rne(acc[i][3]) << 16);
        *(uint2*)&Cb[((r0 + rr + i) * 128 + cc) >> 1] = make_uint2(lo, hi);
    }
}

// ---------------- pull-aggregation over bf16 rows ----------------
// relu=1: relu + write bf16 (hidden layers). relu=0: write fp32 (final).
__global__ __launch_bounds__(256) void k_agg(const unsigned* __restrict__ XWb,
                                             const int* __restrict__ rowptr,
                                             const uint2* __restrict__ meta,
                                             const float* __restrict__ dinv,
                                             const float* __restrict__ bias,
                                             unsigned* __restrict__ outb,
                                             float* __restrict__ outf, int relu, int n) {
    int lane = threadIdx.x & 63;
    int node = blockIdx.x * 4 + (threadIdx.x >> 6);
    if (node >= n) return;

    float di = dinv[node];
    float selfw = di * di;
    unsigned uself = XWb[(size_t)node * 64 + lane];
    float2 bv = *(const float2*)(bias + lane * 2);
    float ax = fmaf(selfw, bf_lo(uself), bv.x);
    float ay = fmaf(selfw, bf_hi(uself), bv.y);

    int p0 = rowptr[node], p1 = rowptr[node + 1];
    for (int base = p0; base < p1; base += 64) {
        int m = p1 - base; if (m > 64) m = 64;
        int idx = base + (lane < m ? lane : m - 1);
        uint2 mv = meta[idx];
        int sv = (int)mv.x;
        float wv = __uint_as_float(mv.y);
        int j = 0;
        for (; j + 4 <= m; j += 4) {
            int s0 = __shfl(sv, j), s1 = __shfl(sv, j + 1);
            int s2 = __shfl(sv, j + 2), s3 = __shfl(sv, j + 3);
            float w0 = __shfl(wv, j), w1 = __shfl(wv, j + 1);
            float w2 = __shfl(wv, j + 2), w3 = __shfl(wv, j + 3);
            unsigned u0 = XWb[(size_t)s0 * 64 + lane];
            unsigned u1 = XWb[(size_t)s1 * 64 + lane];
            unsigned u2 = XWb[(size_t)s2 * 64 + lane];
            unsigned u3 = XWb[(size_t)s3 * 64 + lane];
            ax = fmaf(w0, bf_lo(u0), ax);
            ay = fmaf(w0, bf_hi(u0), ay);
            ax = fmaf(w1, bf_lo(u1), ax);
            ay = fmaf(w1, bf_hi(u1), ay);
            ax = fmaf(w2, bf_lo(u2), ax);
            ay = fmaf(w2, bf_hi(u2), ay);
            ax = fmaf(w3, bf_lo(u3), ax);
            ay = fmaf(w3, bf_hi(u3), ay);
        }
        for (; j < m; ++j) {
            int s = __shfl(sv, j);
            float w = __shfl(wv, j);
            unsigned u = XWb[(size_t)s * 64 + lane];
            ax = fmaf(w, bf_lo(u), ax);
            ay = fmaf(w, bf_hi(u), ay);
        }
    }
    if (relu) {
        ax = fmaxf(ax, 0.0f);
        ay = fmaxf(ay, 0.0f);
        outb[(size_t)node * 64 + lane] = f2bf_rne(ax) | (f2bf_rne(ay) << 16);
    } else {
        *(float2*)(outf + (size_t)node * 128 + lane * 2) = make_float2(ax, ay);
    }
}

// ---------------- launcher ----------------
extern "C" void kernel_launch(void* const* d_in, const int* in_sizes, int n_in,
                              void* d_out, int out_size, void* d_ws, size_t ws_size,
                              hipStream_t stream) {
    const float* x  = (const float*)d_in[0];
    const int*   ei = (const int*)d_in[1];
    const float* ew = (const float*)d_in[2];
    const float* W1 = (const float*)d_in[3];
    const float* b1 = (const float*)d_in[4];
    const float* W2 = (const float*)d_in[5];
    const float* b2 = (const float*)d_in[6];
    const float* W3 = (const float*)d_in[7];
    const float* b3 = (const float*)d_in[8];
    float* out = (float*)d_out;

    const int n = NN, e = NE;
    const int* row = ei;
    const int* col = ei + e;

    char* ws = (char*)d_ws;
    size_t off = 0;
    auto alloc = [&](size_t bytes) -> void* {
        void* p = ws + off;
        off = (off + bytes + 255) & ~(size_t)255;
        return p;
    };
    unsigned*           hb     = (unsigned*)          alloc((size_t)n * 128 * 2);  // bf16 hidden
    unsigned*           xwb    = (unsigned*)          alloc((size_t)n * 128 * 2);  // bf16 xw
    unsigned long long* packed = (unsigned long long*)alloc((size_t)n * 8);
    float*              dinv   = (float*)             alloc((size_t)n * 4);
    int*                rowptr = (int*)               alloc((size_t)(n + 1) * 4);
    int*                rank   = (int*)               alloc((size_t)e * 4);
    uint2*              meta   = (uint2*)             alloc((size_t)e * 8);
    int*                part   = (int*)               alloc(512 * 4);
    (void)ws_size; (void)in_sizes; (void)n_in; (void)out_size;

    int nb = (n + 255) / 256;   // 391
    int eb = (e + 255) / 256;   // 6250
    int gb = n / 32;            // 3125
    int ab = (n + 3) / 4;       // 25000

    k_init<<<nb, 256, 0, stream>>>(packed, n);
    // fused layer-1 GEMM + edge histogram (independent work, overlapped)
    k_gp<<<gb + eb, 256, 0, stream>>>(x, W1, xwb, col, ew, packed, rank, e);
    k_scan1<<<nb, 256, 0, stream>>>(packed, rowptr, part, dinv, n);
    k_scan2<<<1, 512, 0, stream>>>(part, nb);
    k_scan3<<<nb, 256, 0, stream>>>(rowptr, part, n, e);
    k_fill<<<eb, 256, 0, stream>>>(row, col, ew, rowptr, rank, dinv, meta, e);

    // Layer 1 aggregation (xwb from k_gp) -> bf16 hb
    k_agg<<<ab, 256, 0, stream>>>(xwb, rowptr, meta, dinv, b1, hb, (float*)nullptr, 1, n);
    // Layer 2
    k_gemm_b<<<gb, 256, 0, stream>>>(hb, W2, xwb);
    k_agg<<<ab, 256, 0, stream>>>(xwb, rowptr, meta, dinv, b2, hb, (float*)nullptr, 1, n);
    // Layer 3 (fp32 out, no relu)
    k_gemm_b<<<gb, 256, 0, stream>>>(hb, W3, xwb);
    k_agg<<<ab, 256, 0, stream>>>(xwb, rowptr, meta, dinv, b3, (unsigned*)nullptr, out, 0, n);
}

// Round 6
// 519.284 us; speedup vs baseline: 1.8980x; 1.0498x over previous
//
#include <hip/hip_runtime.h>

#define NN 100000
#define NE 1600000

// bf16 helpers
static __device__ __forceinline__ unsigned f2bf_rne(float f) {
    unsigned u = __float_as_uint(f);
    return (u + 0x7FFFu + ((u >> 16) & 1u)) >> 16;   // round-to-nearest-even
}
static __device__ __forceinline__ float bf_lo(unsigned u) { return __uint_as_float(u << 16); }
static __device__ __forceinline__ float bf_hi(unsigned u) { return __uint_as_float(u & 0xFFFF0000u); }

__global__ __launch_bounds__(256) void k_init(unsigned long long* packed, int n) {
    int i = blockIdx.x * 256 + threadIdx.x;
    if (i < n) packed[i] = 0ull;
}

// GEMM core: 32 rows x 128 cols, W staged in 32-row k-chunks (16 KB sW + 16 KB sA
// = 32 KB LDS -> 5 blocks/CU instead of 2 at 80 KB). sA must be pre-filled.
template <typename STORE>
static __device__ __forceinline__ void gemm_core(const float* __restrict__ W,
                                                 float* sW, const float* sA,
                                                 int t, size_t r0, STORE&& store) {
    int rr = (t >> 5) << 2;
    int cc = (t & 31) << 2;
    float acc[4][4] = {{0.0f}};
    const float4* W4 = (const float4*)W;
    float4* sW4 = (float4*)sW;

    for (int kc = 0; kc < 128; kc += 32) {
        // stage W[kc..kc+32) x 128 : 1024 float4, 4 per thread
#pragma unroll
        for (int i = 0; i < 4; ++i) sW4[t + 256 * i] = W4[(kc * 32) + t + 256 * i];
        __syncthreads();
#pragma unroll 2
        for (int k = 0; k < 32; k += 4) {
            float4 w0 = *(const float4*)&sW[(k + 0) * 128 + cc];
            float4 w1 = *(const float4*)&sW[(k + 1) * 128 + cc];
            float4 w2 = *(const float4*)&sW[(k + 2) * 128 + cc];
            float4 w3 = *(const float4*)&sW[(k + 3) * 128 + cc];
#pragma unroll
            for (int i = 0; i < 4; ++i) {
                float4 a = *(const float4*)&sA[(rr + i) * 128 + kc + k];
                acc[i][0] = fmaf(a.x, w0.x, acc[i][0]);
                acc[i][1] = fmaf(a.x, w0.y, acc[i][1]);
                acc[i][2] = fmaf(a.x, w0.z, acc[i][2]);
                acc[i][3] = fmaf(a.x, w0.w, acc[i][3]);
                acc[i][0] = fmaf(a.y, w1.x, acc[i][0]);
                acc[i][1] = fmaf(a.y, w1.y, acc[i][1]);
                acc[i][2] = fmaf(a.y, w1.z, acc[i][2]);
                acc[i][3] = fmaf(a.y, w1.w, acc[i][3]);
                acc[i][0] = fmaf(a.z, w2.x, acc[i][0]);
                acc[i][1] = fmaf(a.z, w2.y, acc[i][1]);
                acc[i][2] = fmaf(a.z, w2.z, acc[i][2]);
                acc[i][3] = fmaf(a.z, w2.w, acc[i][3]);
                acc[i][0] = fmaf(a.w, w3.x, acc[i][0]);
                acc[i][1] = fmaf(a.w, w3.y, acc[i][1]);
                acc[i][2] = fmaf(a.w, w3.z, acc[i][2]);
                acc[i][3] = fmaf(a.w, w3.w, acc[i][3]);
            }
        }
        __syncthreads();
    }
    store(rr, cc, acc);
}

// ---------------- fused: layer-1 GEMM (fp32 A) || edge histogram pass ----------------
// 9375 blocks = 3125 GEMM (b%3==0) + 6250 pass1. 32 KB LDS -> 5 blocks/CU so the
// atomic-bound pass1 blocks keep high concurrency while GEMM blocks overlap.
__global__ __launch_bounds__(256) void k_gp(const float* __restrict__ A,
                                            const float* __restrict__ W,
                                            unsigned* __restrict__ Cb,
                                            const int* __restrict__ col,
                                            const float* __restrict__ ew,
                                            unsigned long long* packed,
                                            int* __restrict__ rank, int e) {
    __shared__ float sW[32 * 128];
    __shared__ float sA[32 * 128];
    int b = blockIdx.x;
    int sub = b % 3;
    int q = b / 3;
    int t = threadIdx.x;

    if (sub != 0) {
        int p = q * 2 + sub - 1;            // 0..6249
        int i = p * 256 + t;
        if (i < e) {
            int c = col[i];
            unsigned fe = (unsigned)__float2uint_rn(ew[i] * 1048576.0f);  // 20 frac bits
            unsigned long long inc = ((unsigned long long)fe << 24) | 1ull;
            unsigned long long old = atomicAdd(&packed[c], inc);
            rank[i] = (int)(old & 0xFFFFFFull);
        }
        return;
    }

    size_t r0 = (size_t)q * 32;
    const float4* A4 = (const float4*)(A + r0 * 128);
    float4* sA4 = (float4*)sA;
#pragma unroll
    for (int i = 0; i < 4; ++i) sA4[t + 256 * i] = A4[t + 256 * i];
    // gemm_core's first __syncthreads covers sA visibility

    gemm_core(W, sW, sA, t, r0, [&](int rr, int cc, float acc[4][4]) {
#pragma unroll
        for (int i = 0; i < 4; ++i) {
            unsigned lo = f2bf_rne(acc[i][0]) | (f2bf_rne(acc[i][1]) << 16);
            unsigned hi = f2bf_rne(acc[i][2]) | (f2bf_rne(acc[i][3]) << 16);
            *(uint2*)&Cb[((r0 + rr + i) * 128 + cc) >> 1] = make_uint2(lo, hi);
        }
    });
}

// fused: exclusive scan of counts -> rowptr, plus dinv = rsqrt(deg)
__global__ __launch_bounds__(256) void k_scan1(const unsigned long long* __restrict__ packed,
                                               int* __restrict__ rowptr,
                                               int* __restrict__ part,
                                               float* __restrict__ dinv, int n) {
    __shared__ int s[256];
    int t = threadIdx.x;
    int i = blockIdx.x * 256 + t;
    unsigned long long pk = (i < n) ? packed[i] : 0ull;
    int v = (int)(pk & 0xFFFFFFull);
    if (i < n) {
        float deg = 1.0f + (float)(pk >> 24) * (1.0f / 1048576.0f);  // +1 self-loop
        dinv[i] = rsqrtf(deg);
    }
    s[t] = v;
    __syncthreads();
    for (int d = 1; d < 256; d <<= 1) {
        int y = (t >= d) ? s[t - d] : 0;
        __syncthreads();
        s[t] += y;
        __syncthreads();
    }
    if (i < n) rowptr[i] = s[t] - v;
    if (t == 255) part[blockIdx.x] = s[255];
}

__global__ __launch_bounds__(512) void k_scan2(int* part, int m) {
    __shared__ int s[512];
    int t = threadIdx.x;
    int v = (t < m) ? part[t] : 0;
    s[t] = v;
    __syncthreads();
    for (int d = 1; d < 512; d <<= 1) {
        int y = (t >= d) ? s[t - d] : 0;
        __syncthreads();
        s[t] += y;
        __syncthreads();
    }
    if (t < m) part[t] = s[t] - v;
}

__global__ __launch_bounds__(256) void k_scan3(int* rowptr, const int* __restrict__ part, int n, int e) {
    int i = blockIdx.x * 256 + threadIdx.x;
    if (i < n) rowptr[i] += part[blockIdx.x];
    if (i == 0) rowptr[n] = e;
}

// atomic-free CSR fill; (src, wn) packed -> one 8-byte scattered store per edge
__global__ __launch_bounds__(256) void k_fill(const int* __restrict__ row,
                                              const int* __restrict__ col,
                                              const float* __restrict__ ew,
                                              const int* __restrict__ rowptr,
                                              const int* __restrict__ rank,
                                              const float* __restrict__ dinv,
                                              uint2* __restrict__ meta, int e) {
    int i = blockIdx.x * 256 + threadIdx.x;
    if (i < e) {
        int c = col[i];
        int r = row[i];
        int p = rowptr[c] + rank[i];
        float w = dinv[r] * ew[i] * dinv[c];
        meta[p] = make_uint2((unsigned)r, __float_as_uint(w));
    }
}

// ---------------- GEMM with bf16 A (layers 2,3) -> bf16 out ----------------
__global__ __launch_bounds__(256) void k_gemm_b(const unsigned* __restrict__ Ab,
                                                const float* __restrict__ W,
                                                unsigned* __restrict__ Cb) {
    __shared__ float sW[32 * 128];
    __shared__ float sA[32 * 128];
    int t = threadIdx.x;
    size_t r0 = (size_t)blockIdx.x * 32;

    const uint2* A2 = (const uint2*)(Ab + r0 * 64);
#pragma unroll
    for (int i = 0; i < 4; ++i) {
        int j = t + 256 * i;
        uint2 u = A2[j];
        float4 f = make_float4(bf_lo(u.x), bf_hi(u.x), bf_lo(u.y), bf_hi(u.y));
        *(float4*)&sA[4 * j] = f;
    }

    gemm_core(W, sW, sA, t, r0, [&](int rr, int cc, float acc[4][4]) {
#pragma unroll
        for (int i = 0; i < 4; ++i) {
            unsigned lo = f2bf_rne(acc[i][0]) | (f2bf_rne(acc[i][1]) << 16);
            unsigned hi = f2bf_rne(acc[i][2]) | (f2bf_rne(acc[i][3]) << 16);
            *(uint2*)&Cb[((r0 + rr + i) * 128 + cc) >> 1] = make_uint2(lo, hi);
        }
    });
}

// ---------------- pull-aggregation over bf16 rows ----------------
// One wave per node; lane owns one bf16 pair. 8 gathers in flight per lane.
__global__ __launch_bounds__(256) void k_agg(const unsigned* __restrict__ XWb,
                                             const int* __restrict__ rowptr,
                                             const uint2* __restrict__ meta,
                                             const float* __restrict__ dinv,
                                             const float* __restrict__ bias,
                                             unsigned* __restrict__ outb,
                                             float* __restrict__ outf, int relu, int n) {
    int lane = threadIdx.x & 63;
    int node = blockIdx.x * 4 + (threadIdx.x >> 6);
    if (node >= n) return;

    float di = dinv[node];
    float selfw = di * di;
    unsigned uself = XWb[(size_t)node * 64 + lane];
    float2 bv = *(const float2*)(bias + lane * 2);
    float ax = fmaf(selfw, bf_lo(uself), bv.x);
    float ay = fmaf(selfw, bf_hi(uself), bv.y);

    int p0 = rowptr[node], p1 = rowptr[node + 1];
    for (int base = p0; base < p1; base += 64) {
        int m = p1 - base; if (m > 64) m = 64;
        int idx = base + (lane < m ? lane : m - 1);
        uint2 mv = meta[idx];
        int sv = (int)mv.x;
        float wv = __uint_as_float(mv.y);
        int j = 0;
        for (; j + 8 <= m; j += 8) {
            int s0 = __shfl(sv, j),     s1 = __shfl(sv, j + 1);
            int s2 = __shfl(sv, j + 2), s3 = __shfl(sv, j + 3);
            int s4 = __shfl(sv, j + 4), s5 = __shfl(sv, j + 5);
            int s6 = __shfl(sv, j + 6), s7 = __shfl(sv, j + 7);
            float w0 = __shfl(wv, j),     w1 = __shfl(wv, j + 1);
            float w2 = __shfl(wv, j + 2), w3 = __shfl(wv, j + 3);
            float w4 = __shfl(wv, j + 4), w5 = __shfl(wv, j + 5);
            float w6 = __shfl(wv, j + 6), w7 = __shfl(wv, j + 7);
            unsigned u0 = XWb[(size_t)s0 * 64 + lane];
            unsigned u1 = XWb[(size_t)s1 * 64 + lane];
            unsigned u2 = XWb[(size_t)s2 * 64 + lane];
            unsigned u3 = XWb[(size_t)s3 * 64 + lane];
            unsigned u4 = XWb[(size_t)s4 * 64 + lane];
            unsigned u5 = XWb[(size_t)s5 * 64 + lane];
            unsigned u6 = XWb[(size_t)s6 * 64 + lane];
            unsigned u7 = XWb[(size_t)s7 * 64 + lane];
            ax = fmaf(w0, bf_lo(u0), ax);  ay = fmaf(w0, bf_hi(u0), ay);
            ax = fmaf(w1, bf_lo(u1), ax);  ay = fmaf(w1, bf_hi(u1), ay);
            ax = fmaf(w2, bf_lo(u2), ax);  ay = fmaf(w2, bf_hi(u2), ay);
            ax = fmaf(w3, bf_lo(u3), ax);  ay = fmaf(w3, bf_hi(u3), ay);
            ax = fmaf(w4, bf_lo(u4), ax);  ay = fmaf(w4, bf_hi(u4), ay);
            ax = fmaf(w5, bf_lo(u5), ax);  ay = fmaf(w5, bf_hi(u5), ay);
            ax = fmaf(w6, bf_lo(u6), ax);  ay = fmaf(w6, bf_hi(u6), ay);
            ax = fmaf(w7, bf_lo(u7), ax);  ay = fmaf(w7, bf_hi(u7), ay);
        }
        for (; j + 4 <= m; j += 4) {
            int s0 = __shfl(sv, j),     s1 = __shfl(sv, j + 1);
            int s2 = __shfl(sv, j + 2), s3 = __shfl(sv, j + 3);
            float w0 = __shfl(wv, j),     w1 = __shfl(wv, j + 1);
            float w2 = __shfl(wv, j + 2), w3 = __shfl(wv, j + 3);
            unsigned u0 = XWb[(size_t)s0 * 64 + lane];
            unsigned u1 = XWb[(size_t)s1 * 64 + lane];
            unsigned u2 = XWb[(size_t)s2 * 64 + lane];
            unsigned u3 = XWb[(size_t)s3 * 64 + lane];
            ax = fmaf(w0, bf_lo(u0), ax);  ay = fmaf(w0, bf_hi(u0), ay);
            ax = fmaf(w1, bf_lo(u1), ax);  ay = fmaf(w1, bf_hi(u1), ay);
            ax = fmaf(w2, bf_lo(u2), ax);  ay = fmaf(w2, bf_hi(u2), ay);
            ax = fmaf(w3, bf_lo(u3), ax);  ay = fmaf(w3, bf_hi(u3), ay);
        }
        for (; j < m; ++j) {
            int s = __shfl(sv, j);
            float w = __shfl(wv, j);
            unsigned u = XWb[(size_t)s * 64 + lane];
            ax = fmaf(w, bf_lo(u), ax);
            ay = fmaf(w, bf_hi(u), ay);
        }
    }
    if (relu) {
        ax = fmaxf(ax, 0.0f);
        ay = fmaxf(ay, 0.0f);
        outb[(size_t)node * 64 + lane] = f2bf_rne(ax) | (f2bf_rne(ay) << 16);
    } else {
        *(float2*)(outf + (size_t)node * 128 + lane * 2) = make_float2(ax, ay);
    }
}

// ---------------- launcher ----------------
extern "C" void kernel_launch(void* const* d_in, const int* in_sizes, int n_in,
                              void* d_out, int out_size, void* d_ws, size_t ws_size,
                              hipStream_t stream) {
    const float* x  = (const float*)d_in[0];
    const int*   ei = (const int*)d_in[1];
    const float* ew = (const float*)d_in[2];
    const float* W1 = (const float*)d_in[3];
    const float* b1 = (const float*)d_in[4];
    const float* W2 = (const float*)d_in[5];
    const float* b2 = (const float*)d_in[6];
    const float* W3 = (const float*)d_in[7];
    const float* b3 = (const float*)d_in[8];
    float* out = (float*)d_out;

    const int n = NN, e = NE;
    const int* row = ei;
    const int* col = ei + e;

    char* ws = (char*)d_ws;
    size_t off = 0;
    auto alloc = [&](size_t bytes) -> void* {
        void* p = ws + off;
        off = (off + bytes + 255) & ~(size_t)255;
        return p;
    };
    unsigned*           hb     = (unsigned*)          alloc((size_t)n * 128 * 2);
    unsigned*           xwb    = (unsigned*)          alloc((size_t)n * 128 * 2);
    unsigned long long* packed = (unsigned long long*)alloc((size_t)n * 8);
    float*              dinv   = (float*)             alloc((size_t)n * 4);
    int*                rowptr = (int*)               alloc((size_t)(n + 1) * 4);
    int*                rank   = (int*)               alloc((size_t)e * 4);
    uint2*              meta   = (uint2*)             alloc((size_t)e * 8);
    int*                part   = (int*)               alloc(512 * 4);
    (void)ws_size; (void)in_sizes; (void)n_in; (void)out_size;

    int nb = (n + 255) / 256;   // 391
    int eb = (e + 255) / 256;   // 6250
    int gb = n / 32;            // 3125
    int ab = (n + 3) / 4;       // 25000

    k_init<<<nb, 256, 0, stream>>>(packed, n);
    k_gp<<<gb + eb, 256, 0, stream>>>(x, W1, xwb, col, ew, packed, rank, e);
    k_scan1<<<nb, 256, 0, stream>>>(packed, rowptr, part, dinv, n);
    k_scan2<<<1, 512, 0, stream>>>(part, nb);
    k_scan3<<<nb, 256, 0, stream>>>(rowptr, part, n, e);
    k_fill<<<eb, 256, 0, stream>>>(row, col, ew, rowptr, rank, dinv, meta, e);

    // Layer 1 aggregation -> bf16 hb
    k_agg<<<ab, 256, 0, stream>>>(xwb, rowptr, meta, dinv, b1, hb, (float*)nullptr, 1, n);
    // Layer 2
    k_gemm_b<<<gb, 256, 0, stream>>>(hb, W2, xwb);
    k_agg<<<ab, 256, 0, stream>>>(xwb, rowptr, meta, dinv, b2, hb, (float*)nullptr, 1, n);
    // Layer 3 (fp32 out, no relu)
    k_gemm_b<<<gb, 256, 0, stream>>>(hb, W3, xwb);
    k_agg<<<ab, 256, 0, stream>>>(xwb, rowptr, meta, dinv, b3, (unsigned*)nullptr, out, 0, n);
}